// Round 1
// baseline (765.827 us; speedup 1.0000x reference)
//
#include <hip/hip_runtime.h>
#include <hip/hip_bf16.h>

typedef _Float16 f16;
typedef _Float16 f16x8 __attribute__((ext_vector_type(8)));
typedef float f32x4 __attribute__((ext_vector_type(4)));

#define NBATCH 128
#define NTIME  128
#define NKIN   512
#define NUNITS 512
#define NGATE  2048

static __device__ __forceinline__ float sigmoidf_(float x) {
    return 1.0f / (1.0f + __expf(-x));
}
// overflow-safe tanh
static __device__ __forceinline__ float tanhf_(float x) {
    float t = __expf(-2.0f * fabsf(x));
    float r = (1.0f - t) / (1.0f + t);
    return copysignf(r, x);
}

static __device__ __forceinline__ f16x8 pack8(float4 a, float4 b) {
    f16x8 r;
    r[0] = (f16)a.x; r[1] = (f16)a.y; r[2] = (f16)a.z; r[3] = (f16)a.w;
    r[4] = (f16)b.x; r[5] = (f16)b.y; r[6] = (f16)b.z; r[7] = (f16)b.w;
    return r;
}

// ---------------- transpose: f32 in[512][2048] -> f16 out[2048][512] ----------------
// out[c][r] = in[r][c]. grid (2048/64, 512/64) = (32, 8), 256 threads.
__global__ __launch_bounds__(256)
void k_transpose(const float* __restrict__ in, f16* __restrict__ out) {
    __shared__ f16 tile[64][72];   // pad 8 f16 = 16B keeps alignment, breaks conflicts
    const int c0 = blockIdx.x * 64;
    const int r0 = blockIdx.y * 64;
    const int tid = threadIdx.x;
    {
        const int lr = tid >> 2;          // 0..63
        const int lc = (tid & 3) << 4;    // 0,16,32,48
        const float* src = in + (size_t)(r0 + lr) * NGATE + c0 + lc;
        float4 v0 = ((const float4*)src)[0];
        float4 v1 = ((const float4*)src)[1];
        float4 v2 = ((const float4*)src)[2];
        float4 v3 = ((const float4*)src)[3];
        *(f16x8*)&tile[lr][lc]     = pack8(v0, v1);
        *(f16x8*)&tile[lr][lc + 8] = pack8(v2, v3);
    }
    __syncthreads();
    {
        const int lc = tid >> 2;          // output row within tile (input col)
        const int lr = (tid & 3) << 4;    // output col start (input row)
        f16x8 a, b;
#pragma unroll
        for (int i = 0; i < 8; ++i) a[i] = tile[lr + i][lc];
#pragma unroll
        for (int i = 0; i < 8; ++i) b[i] = tile[lr + 8 + i][lc];
        f16* dst = out + (size_t)(c0 + lc) * NKIN + r0 + lr;
        *(f16x8*)dst       = a;
        *(f16x8*)(dst + 8) = b;
    }
}

// ---------------- projection: xz[m][n] = x[m][:] @ W[:][n] + bias[n] ----------------
// x: f32 [16384][512]; Wt: f16 [2048][512] (Wt[n][k] = W[k][n]); xz: f16 [16384][2048]
// BM=128, BN=64, BK=32; 256 threads = 4 waves arranged 2(M) x 2(N); wave tile 64x32.
__global__ __launch_bounds__(256)
void k_proj(const float* __restrict__ x, const f16* __restrict__ Wt,
            const float* __restrict__ bias, f16* __restrict__ xz) {
    __shared__ f16 As[128][40];   // [m][k], pad 8
    __shared__ f16 Bs[64][40];    // [n][k], pad 8
    const int n0 = blockIdx.x * 64;
    const int m0 = blockIdx.y * 128;
    const int tid  = threadIdx.x;
    const int lane = tid & 63;
    const int wid  = tid >> 6;
    const int wm = (wid >> 1) * 64;
    const int wn = (wid & 1) * 32;
    const int lm = lane & 15;
    const int lg = lane >> 4;

    f32x4 acc[4][2];
#pragma unroll
    for (int mi = 0; mi < 4; ++mi)
#pragma unroll
        for (int ni = 0; ni < 2; ++ni)
#pragma unroll
            for (int i = 0; i < 4; ++i) acc[mi][ni][i] = 0.0f;

    for (int kt = 0; kt < NKIN; kt += 32) {
        // stage A (f32 -> f16): 128 rows x 32 k
        {
            const int row = tid >> 1;
            const int kq  = (tid & 1) << 4;
            const float* src = x + (size_t)(m0 + row) * NKIN + kt + kq;
            float4 v0 = ((const float4*)src)[0];
            float4 v1 = ((const float4*)src)[1];
            float4 v2 = ((const float4*)src)[2];
            float4 v3 = ((const float4*)src)[3];
            *(f16x8*)&As[row][kq]     = pack8(v0, v1);
            *(f16x8*)&As[row][kq + 8] = pack8(v2, v3);
        }
        // stage B: 64 n-rows x 32 k from Wt
        {
            const int nrow = tid >> 2;
            const int kq   = (tid & 3) << 3;
            f16x8 v = *(const f16x8*)(Wt + (size_t)(n0 + nrow) * NKIN + kt + kq);
            *(f16x8*)&Bs[nrow][kq] = v;
        }
        __syncthreads();
        f16x8 a[4], b[2];
#pragma unroll
        for (int mi = 0; mi < 4; ++mi)
            a[mi] = *(const f16x8*)&As[wm + mi * 16 + lm][lg * 8];
#pragma unroll
        for (int ni = 0; ni < 2; ++ni)
            b[ni] = *(const f16x8*)&Bs[wn + ni * 16 + lm][lg * 8];
#pragma unroll
        for (int mi = 0; mi < 4; ++mi)
#pragma unroll
            for (int ni = 0; ni < 2; ++ni)
                acc[mi][ni] = __builtin_amdgcn_mfma_f32_16x16x32_f16(a[mi], b[ni], acc[mi][ni], 0, 0, 0);
        __syncthreads();
    }
    // epilogue: C row = (lane>>4)*4 + reg, col = lane&15  [guide-verified layout]
#pragma unroll
    for (int mi = 0; mi < 4; ++mi) {
#pragma unroll
        for (int ni = 0; ni < 2; ++ni) {
            const int col = n0 + wn + ni * 16 + lm;
            const float bv = bias[col];
#pragma unroll
            for (int i = 0; i < 4; ++i) {
                const int row = m0 + wm + mi * 16 + lg * 4 + i;
                xz[(size_t)row * NGATE + col] = (f16)(acc[mi][ni][i] + bv);
            }
        }
    }
}

// ---------------- one LSTM timestep ----------------
// grid (32 unit-groups, 8 batch-groups), 256 threads = 4 waves; wave w computes gate w.
// z[b][gcol] = xz[b][t][gcol] + h_in[b][:] @ U[:][gcol]
__global__ __launch_bounds__(256)
void k_step(const int t, const f16* __restrict__ xz, const f16* __restrict__ Ut,
            const f16* __restrict__ h_in, f16* __restrict__ h_out,
            float* __restrict__ c_st, float* __restrict__ out) {
    __shared__ f16 As[16][520];       // h rows, pad 8
    __shared__ f16 Bs[64][520];       // U cols (4 gates x 16 units), pad 8
    __shared__ float zs[4][16][17];   // gate exchange
    const int ug = blockIdx.x;
    const int bg = blockIdx.y;
    const int r0 = bg * 16;
    const int u0 = ug * 16;
    const int tid  = threadIdx.x;
    const int lane = tid & 63;
    const int g    = tid >> 6;    // wave id == gate (0:i 1:f 2:g 3:o)
    const int lm = lane & 15;
    const int lg = lane >> 4;

    // stage A: 16 rows x 512 of h_in
    {
        const int row = tid >> 4;
        const int kq  = (tid & 15) << 5;
        const f16* src = h_in + (size_t)(r0 + row) * NUNITS + kq;
#pragma unroll
        for (int q = 0; q < 4; ++q)
            *(f16x8*)&As[row][kq + q * 8] = *(const f16x8*)(src + q * 8);
    }
    // stage B: 64 gate-cols x 512 from Ut
    {
        const int c  = tid >> 2;
        const int kq = (tid & 3) << 7;
        const int gcol = (c >> 4) * NUNITS + u0 + (c & 15);
        const f16* src = Ut + (size_t)gcol * NUNITS + kq;
#pragma unroll
        for (int q = 0; q < 16; ++q)
            *(f16x8*)&Bs[c][kq + q * 8] = *(const f16x8*)(src + q * 8);
    }
    // init accumulator from xz (folds the add)
    f32x4 acc;
    {
        const int colg = g * NUNITS + u0 + lm;
#pragma unroll
        for (int i = 0; i < 4; ++i) {
            const int b = r0 + lg * 4 + i;
            acc[i] = (float)xz[((size_t)b * NTIME + t) * NGATE + colg];
        }
    }
    __syncthreads();
    // K loop: 16 x mfma 16x16x32
#pragma unroll
    for (int kk = 0; kk < NUNITS; kk += 32) {
        f16x8 a = *(const f16x8*)&As[lm][kk + lg * 8];
        f16x8 b = *(const f16x8*)&Bs[g * 16 + lm][kk + lg * 8];
        acc = __builtin_amdgcn_mfma_f32_16x16x32_f16(a, b, acc, 0, 0, 0);
    }
    // exchange gates via LDS
#pragma unroll
    for (int i = 0; i < 4; ++i)
        zs[g][lg * 4 + i][lm] = acc[i];
    __syncthreads();
    // state update: one thread per (row, unit)
    const int row = tid >> 4;
    const int uu  = tid & 15;
    const float zi = zs[0][row][uu];
    const float zf = zs[1][row][uu];
    const float zg = zs[2][row][uu];
    const float zo = zs[3][row][uu];
    const int gidx = (r0 + row) * NUNITS + u0 + uu;
    const float cold = c_st[gidx];
    const float iv = sigmoidf_(zi);
    const float fv = sigmoidf_(zf);
    const float gv = tanhf_(zg);
    const float ov = sigmoidf_(zo);
    const float cn = fv * cold + iv * gv;
    const float hn = ov * tanhf_(cn);
    c_st[gidx] = cn;
    h_out[gidx] = (f16)hn;
    if (t == NTIME - 1) {
        out[gidx]               = hn;   // last_h
        out[65536 + gidx]       = hn;   // state_h
        out[131072 + gidx]      = cn;   // state_c
    }
}

extern "C" void kernel_launch(void* const* d_in, const int* in_sizes, int n_in,
                              void* d_out, int out_size, void* d_ws, size_t ws_size,
                              hipStream_t stream) {
    const float* x    = (const float*)d_in[0];
    const float* W    = (const float*)d_in[1];
    const float* U    = (const float*)d_in[2];
    const float* bias = (const float*)d_in[3];
    float* out = (float*)d_out;
    char* ws = (char*)d_ws;

    size_t off = 0;
    f16* Wt = (f16*)(ws + off); off += (size_t)NGATE * NKIN * 2;            // 2 MB
    f16* Ut = (f16*)(ws + off); off += (size_t)NGATE * NUNITS * 2;         // 2 MB
    f16* xz = (f16*)(ws + off); off += (size_t)NBATCH * NTIME * NGATE * 2; // 64 MB
    f16* h0 = (f16*)(ws + off); off += (size_t)NBATCH * NUNITS * 2;
    f16* h1 = (f16*)(ws + off); off += (size_t)NBATCH * NUNITS * 2;
    float* c_st = (float*)(ws + off); off += (size_t)NBATCH * NUNITS * 4;
    if (ws_size < off) return;  // insufficient scratch -> fail visibly (outputs stay zero)

    hipMemsetAsync(h0,   0, (size_t)NBATCH * NUNITS * 2, stream);
    hipMemsetAsync(c_st, 0, (size_t)NBATCH * NUNITS * 4, stream);

    k_transpose<<<dim3(32, 8), 256, 0, stream>>>(W, Wt);
    k_transpose<<<dim3(32, 8), 256, 0, stream>>>(U, Ut);
    k_proj<<<dim3(32, 128), 256, 0, stream>>>(x, Wt, bias, xz);

    for (int t = 0; t < NTIME; ++t) {
        const f16* hi = (t & 1) ? h1 : h0;
        f16*       ho = (t & 1) ? h0 : h1;
        k_step<<<dim3(32, 8), 256, 0, stream>>>(t, xz, Ut, hi, ho, c_st, out);
    }
}